// Round 5
// baseline (143.114 us; speedup 1.0000x reference)
//
#include <hip/hip_runtime.h>

// VQ-VAE forward: out = code_out[argmax_c(logits_c(x))], hard_idx = argmax.
// logits are piecewise-linear in scalar x (128 relu breakpoints). Per interval
// we build the UPPER ENVELOPE of the 512 affine logit lines (fp64-exact,
// branchless pairwise L/U-bound formulation). The per-interval envelopes are
// then flattened into ONE globally x-sorted segment table gxs/gval, plus a
// 4096-bucket accelerator keyed on the monotone-uint of the fp32 bits of x,
// so each sample needs ~1 LDS read + ~1 global read (usually zero search).

#define B_SAMPLES 262144
#define HIDDEN    128
#define NUM_CODES 512
#define EMBED_DIM 256
#define NUM_INT   129     // HIDDEN + 1 intervals
#define MAXSEG    (NUM_INT * NUM_CODES)
#define NBUCK     4096

// ---- workspace layout (byte offsets) ----
// 0       : t_sorted[128] double
// 2048    : code_out[512] double
// 8192    : env_cnt[129] int
// 12288   : gM[1] int
// 16384   : gbuck[4097] int
// 36864   : surv[MAXSEG] uchar
// 106496  : Lx[MAXSEG] double
// 638976  : AB[MAXSEG] double2
// 1703936 : env_xs[MAXSEG] double
// 2236416 : env_idx[MAXSEG] int
// 2502656 : gxs[MAXSEG] double
// 3031040 : gval[MAXSEG] float2      -> total ~3.6 MB

// P0: blockIdx 0 = thresholds sort + env_cnt zero; blocks 1,2 = code_out.
__global__ void __launch_bounds__(256) k_prep0(
    const float* __restrict__ w1, const float* __restrict__ b1,
    const float* __restrict__ emb, const float* __restrict__ decw,
    const float* __restrict__ decb, double* __restrict__ t_sorted,
    double* __restrict__ code_out, int* __restrict__ env_cnt) {
  const int tid = threadIdx.x;
  if (blockIdx.x == 0) {
    __shared__ double tloc[HIDDEN];
    if (tid < HIDDEN) {
      double w = (double)w1[tid], b = (double)b1[tid];
      double t = -b / w;
      if (!isfinite(t)) t = 1e30;
      t = fmin(fmax(t, -1e30), 1e30);
      tloc[tid] = t;
    }
    if (tid < NUM_INT) env_cnt[tid] = 0;
    __syncthreads();
    if (tid < HIDDEN) {                   // stable rank sort, O(128^2)
      double t = tloc[tid];
      int r = 0;
      for (int k = 0; k < HIDDEN; ++k) {
        double tk = tloc[k];
        r += (tk < t) || (tk == t && k < tid);
      }
      t_sorted[r] = t;
    }
  } else {
    __shared__ double sdw[EMBED_DIM];
    sdw[tid] = (double)decw[tid];
    __syncthreads();
    const int c = (blockIdx.x - 1) * 256 + tid;
    const float4* e4 = (const float4*)(emb + c * EMBED_DIM);
    double s = 0.0;
    #pragma unroll 8
    for (int q = 0; q < EMBED_DIM / 4; ++q) {
      const float4 v = e4[q];
      const int j = q * 4;
      s = fma((double)v.x, sdw[j + 0], s);
      s = fma((double)v.y, sdw[j + 1], s);
      s = fma((double)v.z, sdw[j + 2], s);
      s = fma((double)v.w, sdw[j + 3], s);
    }
    code_out[c] = s + (double)decb[0];
  }
}

// P1: per-interval affine (A,B). Thread = (interval, code-half); float4 stream.
__global__ void __launch_bounds__(256) k_tables(
    const float* __restrict__ w1, const float* __restrict__ b1,
    const float* __restrict__ w2, const float* __restrict__ b2,
    const double* __restrict__ t_sorted, double2* __restrict__ AB) {
  __shared__ double wj[HIDDEN], bj[HIDDEN];
  const int i = blockIdx.x >> 1;
  const int c = ((blockIdx.x & 1) << 8) + threadIdx.x;
  const int tid = threadIdx.x;
  double xm;
  if (i == 0)            xm = t_sorted[0] - 1.0;
  else if (i == HIDDEN)  xm = t_sorted[HIDDEN - 1] + 1.0;
  else                   xm = 0.5 * (t_sorted[i - 1] + t_sorted[i]);
  if (tid < HIDDEN) {
    double w = (double)w1[tid], b = (double)b1[tid];
    bool act = fma(w, xm, b) > 0.0;       // relu sign constant in open interval
    wj[tid] = act ? w : 0.0;
    bj[tid] = act ? b : 0.0;
  }
  __syncthreads();
  const float4* r4 = (const float4*)(w2 + c * HIDDEN);
  double A = 0.0, Bv = 0.0;
  #pragma unroll 8
  for (int q = 0; q < HIDDEN / 4; ++q) {
    const float4 v = r4[q];
    const int j = q * 4;
    A  = fma((double)v.x, wj[j + 0], A);
    A  = fma((double)v.y, wj[j + 1], A);
    A  = fma((double)v.z, wj[j + 2], A);
    A  = fma((double)v.w, wj[j + 3], A);
    Bv = fma((double)v.x, bj[j + 0], Bv);
    Bv = fma((double)v.y, bj[j + 1], Bv);
    Bv = fma((double)v.z, bj[j + 2], Bv);
    Bv = fma((double)v.w, bj[j + 3], Bv);
  }
  AB[(i << 9) + c] = make_double2(A, Bv + (double)b2[c]);
}

// P2: branchless pairwise envelope membership (proven in R2-R4).
// L as (nL,dL) dL>=0 (dL==0 => -inf); U as (nU,dU) dU<=0 (dU==0 => +inf).
__global__ void __launch_bounds__(256) k_env1(const double2* __restrict__ AB,
                       unsigned char* __restrict__ surv, double* __restrict__ Lx,
                       int* __restrict__ env_cnt) {
  __shared__ double2 sAB[NUM_CODES];
  __shared__ double sNL[4][64], sDL[4][64], sNU[4][64], sDU[4][64];
  __shared__ int sDead[4][64];
  const int tid = threadIdx.x;
  const int i = blockIdx.x >> 3;
  const int g = blockIdx.x & 7;
  const int w = tid >> 6, lane = tid & 63;
  const int c = (g << 6) + lane;
  const double2* row = AB + (i << 9);
  for (int t = tid; t < NUM_CODES; t += 256) sAB[t] = row[t];
  __syncthreads();
  const double2 my = sAB[c];
  double nL = -1.0, dL = 0.0, nU = -1.0, dU = 0.0;
  int dead = 0;
  const int k0 = w << 7;
  #pragma unroll 4
  for (int kk = 0; kk < 128; ++kk) {
    const int k = k0 + kk;
    const double2 o = sAB[k];             // wave-uniform -> LDS broadcast
    const double d = my.x - o.x;
    const double n = o.y - my.y;          // x* = n/d
    const bool condL = (d > 0.0) && (n * dL > nL * d);
    const bool condU = (d < 0.0) && (n * dU < nU * d);
    nL = condL ? n : nL;  dL = condL ? d : dL;
    nU = condU ? n : nU;  dU = condU ? d : dU;
    dead |= (d == 0.0) && ((n > 0.0) || (n == 0.0 && k < c));
  }
  sNL[w][lane] = nL; sDL[w][lane] = dL;
  sNU[w][lane] = nU; sDU[w][lane] = dU;
  sDead[w][lane] = dead;
  __syncthreads();
  if (tid < 64) {
    #pragma unroll
    for (int wv = 1; wv < 4; ++wv) {
      double cn = sNL[wv][lane], cd = sDL[wv][lane];
      if (cn * dL > nL * cd) { nL = cn; dL = cd; }
      cn = sNU[wv][lane]; cd = sDU[wv][lane];
      if (cn * dU < nU * cd) { nU = cn; dU = cd; }
      dead |= sDead[wv][lane];
    }
    const int sv = (!dead) && (dL == 0.0 || dU == 0.0 || (nL * dU > nU * dL));
    const int pair = (i << 9) + c;
    surv[pair] = (unsigned char)sv;
    Lx[pair]   = (dL == 0.0) ? -1e300 : nL / dL;
    const unsigned long long m = __ballot(sv);
    if (lane == 0) atomicAdd(&env_cnt[i], (int)__popcll(m));
  }
}

// P3: compact survivors into per-interval slope-sorted segment tables.
__global__ void __launch_bounds__(256) k_env2(const double2* __restrict__ AB,
                       const unsigned char* __restrict__ surv,
                       const double* __restrict__ Lx,
                       double* __restrict__ env_xs, int* __restrict__ env_idx) {
  __shared__ double sA[NUM_CODES];
  const int tid = threadIdx.x;
  const int i = blockIdx.x >> 1;
  const int c = ((blockIdx.x & 1) << 8) + tid;
  const int base = i << 9;
  for (int t = tid; t < NUM_CODES; t += 256)
    sA[t] = surv[base + t] ? AB[base + t].x : 1e300;
  __syncthreads();
  const double myA = sA[c];
  int rank = 0;
  #pragma unroll 8
  for (int k = 0; k < NUM_CODES; ++k) rank += (sA[k] < myA) ? 1 : 0;
  if (surv[base + c]) {
    env_xs[base + rank]  = Lx[base + c];
    env_idx[base + rank] = c;
  }
}

// P4: flatten per-interval envelopes into one global x-sorted table.
// Every block redundantly computes all 129 reachable-counts + prefix (cheap),
// then scatters its own interval. Entry 0 of interval i starts at t_{i-1}.
__global__ void __launch_bounds__(256) kg2(
    const double* __restrict__ t_sorted, const int* __restrict__ env_cnt,
    const double* __restrict__ env_xs, const int* __restrict__ env_idx,
    const double* __restrict__ code_out,
    double* __restrict__ gxs, float2* __restrict__ gval, int* __restrict__ gM) {
  __shared__ int scount[NUM_INT], sj0[NUM_INT], soff[NUM_INT + 1];
  const int tid = threadIdx.x;
  if (tid < NUM_INT) {
    const int ii = tid;
    const double tlo = (ii == 0) ? -1e300 : t_sorted[ii - 1];
    const double thi = (ii == NUM_INT - 1) ? 1e300 : t_sorted[ii];
    const int cnt = env_cnt[ii];
    const int base = ii << 9;
    int lo = 0, hi = cnt - 1;             // j0: largest j with xs <= tlo
    while (lo < hi) { int mid = (lo + hi + 1) >> 1; if (env_xs[base + mid] <= tlo) lo = mid; else hi = mid - 1; }
    const int j0 = lo;
    lo = 0; hi = cnt - 1;                 // jend: largest j with xs < thi
    while (lo < hi) { int mid = (lo + hi + 1) >> 1; if (env_xs[base + mid] < thi) lo = mid; else hi = mid - 1; }
    const int jend = lo;
    sj0[ii] = j0;
    scount[ii] = max(0, jend - j0 + 1);   // 0 for empty (duplicate-threshold) intervals
  }
  __syncthreads();
  if (tid <= NUM_INT) soff[tid] = (tid == 0) ? 0 : scount[tid - 1];
  __syncthreads();
  for (int off = 1; off <= NUM_INT; off <<= 1) {   // Hillis-Steele prefix
    int v = 0;
    if (tid <= NUM_INT && tid >= off) v = soff[tid - off];
    __syncthreads();
    if (tid <= NUM_INT) soff[tid] += v;
    __syncthreads();
  }
  const int i = blockIdx.x;
  const int off = soff[i], j0 = sj0[i], cnt_i = scount[i];
  const int base = i << 9;
  const double tlo = (i == 0) ? -1e300 : t_sorted[i - 1];
  for (int k = tid; k < cnt_i; k += 256) {
    const int c = env_idx[base + j0 + k];
    gxs[off + k]  = (k == 0) ? tlo : env_xs[base + j0 + k];
    gval[off + k] = make_float2((float)code_out[c], (float)c);
  }
  if (i == 0 && tid == 0) gM[0] = soff[NUM_INT];
}

// P5: bucket accelerator. gbuck[b] = slot of the bucket's lower-edge x.
__global__ void __launch_bounds__(256) kg3(const double* __restrict__ gxs,
                       const int* __restrict__ gM, int* __restrict__ gbuck) {
  const int b = blockIdx.x * 256 + threadIdx.x;
  const int M = gM[0];
  if (b < NBUCK) {
    const unsigned key = (unsigned)b << 20;
    const unsigned u = (key & 0x80000000u) ? (key ^ 0x80000000u) : ~key;
    const float xf = __uint_as_float(u);
    double xb;
    if (xf != xf) xb = (b >= NBUCK / 2) ? 1e300 : -1e300;  // NaN-prefix buckets
    else          xb = (double)xf;
    int lo = 0, hi = M - 1;
    while (lo < hi) { int mid = (lo + hi + 1) >> 1; if (gxs[mid] <= xb) lo = mid; else hi = mid - 1; }
    gbuck[b] = lo;
  }
  if (b == 0) gbuck[NBUCK] = M - 1;
}

// P6: per-sample lookup: 1 LDS bucket read, usually zero search steps,
// one 8B gval load. 4 samples/thread, float4 in/out.
__global__ void __launch_bounds__(256) k_map(const float* __restrict__ x,
                       const double* __restrict__ gxs,
                       const float2* __restrict__ gval,
                       const int* __restrict__ gbuck,
                       float* __restrict__ out, float* __restrict__ idx_out) {
  __shared__ int sb[NBUCK + 1];
  const int tid = threadIdx.x;
  for (int t = tid; t < NBUCK + 1; t += 256) sb[t] = gbuck[t];
  __syncthreads();
  const int s = blockIdx.x * 1024 + tid * 4;
  const float4 xv4 = *(const float4*)(x + s);
  float o[4], id[4];
  const float xs[4] = {xv4.x, xv4.y, xv4.z, xv4.w};
  #pragma unroll
  for (int k = 0; k < 4; ++k) {
    const float xf = xs[k];
    const double xv = (double)xf;
    const unsigned u = __float_as_uint(xf);
    const unsigned key = (u & 0x80000000u) ? ~u : (u | 0x80000000u);
    const int b = key >> 20;
    int lo = sb[b], hi = sb[b + 1];
    while (lo < hi) {                     // rare: bucket spans >1 segment
      const int mid = (lo + hi + 1) >> 1;
      if (gxs[mid] <= xv) lo = mid; else hi = mid - 1;
    }
    const float2 v = gval[lo];
    o[k] = v.x; id[k] = v.y;
  }
  *(float4*)(out + s)     = make_float4(o[0], o[1], o[2], o[3]);
  *(float4*)(idx_out + s) = make_float4(id[0], id[1], id[2], id[3]);
}

extern "C" void kernel_launch(void* const* d_in, const int* in_sizes, int n_in,
                              void* d_out, int out_size, void* d_ws, size_t ws_size,
                              hipStream_t stream) {
  const float* x    = (const float*)d_in[0];
  const float* w1   = (const float*)d_in[1];
  const float* b1   = (const float*)d_in[2];
  const float* w2   = (const float*)d_in[3];
  const float* b2   = (const float*)d_in[4];
  const float* emb  = (const float*)d_in[5];
  const float* decw = (const float*)d_in[6];
  const float* decb = (const float*)d_in[7];

  char* ws = (char*)d_ws;
  double*        t_sorted = (double*)        (ws + 0);
  double*        code_out = (double*)        (ws + 2048);
  int*           env_cnt  = (int*)           (ws + 8192);
  int*           gM       = (int*)           (ws + 12288);
  int*           gbuck    = (int*)           (ws + 16384);
  unsigned char* surv     = (unsigned char*) (ws + 36864);
  double*        Lx       = (double*)        (ws + 106496);
  double2*       AB       = (double2*)       (ws + 638976);
  double*        env_xs   = (double*)        (ws + 1703936);
  int*           env_idx  = (int*)           (ws + 2236416);
  double*        gxs      = (double*)        (ws + 2502656);
  float2*        gval     = (float2*)        (ws + 3031040);

  float* out  = (float*)d_out;
  float* idxo = out + B_SAMPLES;

  k_prep0 <<<3,                256, 0, stream>>>(w1, b1, emb, decw, decb, t_sorted, code_out, env_cnt);
  k_tables<<<NUM_INT * 2,      256, 0, stream>>>(w1, b1, w2, b2, t_sorted, AB);
  k_env1  <<<NUM_INT * 8,      256, 0, stream>>>(AB, surv, Lx, env_cnt);
  k_env2  <<<NUM_INT * 2,      256, 0, stream>>>(AB, surv, Lx, env_xs, env_idx);
  kg2     <<<NUM_INT,          256, 0, stream>>>(t_sorted, env_cnt, env_xs, env_idx, code_out, gxs, gval, gM);
  kg3     <<<NBUCK / 256,      256, 0, stream>>>(gxs, gM, gbuck);
  k_map   <<<B_SAMPLES / 1024, 256, 0, stream>>>(x, gxs, gval, gbuck, out, idxo);
}